// Round 2
// baseline (202.333 us; speedup 1.0000x reference)
//
#include <hip/hip_runtime.h>
#include <hip/hip_bf16.h>

#define B_DIM 8192
#define D_DIM 2048
#define U_DIM 2048
#define KWORDS 64            // 2048 bits = 64 uint32 words per row/col

// ---------------- Kernel 1: pack input signs via wave ballot ----------------
// x: [B][D] fp32 -> xb: [B][D/64] u64. Each wave handles 256 consecutive
// elements (4 ballots); 4 loads in flight per thread for latency hiding.
__global__ void pack_x_kernel(const float* __restrict__ x,
                              unsigned long long* __restrict__ xb) {
    const int gwave = (blockIdx.x * blockDim.x + threadIdx.x) >> 6;
    const int lane  = threadIdx.x & 63;
    const size_t base = (size_t)gwave * 256;
    float v0 = x[base + lane];
    float v1 = x[base + 64 + lane];
    float v2 = x[base + 128 + lane];
    float v3 = x[base + 192 + lane];
    unsigned long long m0 = __ballot(v0 >= 0.0f);
    unsigned long long m1 = __ballot(v1 >= 0.0f);
    unsigned long long m2 = __ballot(v2 >= 0.0f);
    unsigned long long m3 = __ballot(v3 >= 0.0f);
    if (lane == 0) {
        ulonglong2* p = (ulonglong2*)(xb + (base >> 6));   // 32B-aligned (base%256==0)
        ulonglong2 a; a.x = m0; a.y = m1;
        ulonglong2 b; b.x = m2; b.y = m3;
        p[0] = a;
        p[1] = b;
    }
}

// ---------------- Kernel 2: pack kernel signs (transposed) ----------------
// k: [D][U] fp32 -> kb: [U][D/64] u64 (bits run along D for fixed unit j).
__global__ void pack_k_kernel(const float* __restrict__ k,
                              unsigned long long* __restrict__ kb) {
    __shared__ float tile[64][65];                     // +1 pad: conflict-free column reads
    const int j0 = (blockIdx.x & 31) * 64;
    const int d0 = (blockIdx.x >> 5) * 64;
    const int tid  = threadIdx.x;
    const int lane = tid & 63;
    const int wv   = tid >> 6;                         // 4 waves

    for (int i = 0; i < 16; i++) {
        int row = i * 4 + wv;
        tile[row][lane] = k[(size_t)(d0 + row) * U_DIM + j0 + lane];
    }
    __syncthreads();

    for (int c = wv * 16; c < wv * 16 + 16; c++) {
        float v = tile[lane][c];
        unsigned long long m = __ballot(v >= 0.0f);
        if (lane == 0) kb[(size_t)(j0 + c) * (D_DIM / 64) + (d0 >> 6)] = m;
    }
}

// ---------------- Kernel 3: binary GEMM via xor + popcount ----------------
// out[i][j] = D - 2*popc(xbits[i] ^ kbits[j]) + bias[j]
// 128x128 output tile per block, 256 threads, 8x8 outputs/thread.
// LDS layout XOR-swizzled: word-group w4 of row r lives at column w4^((r>>3)&7).
// -> both the 4-distinct-row xs reads and 16-distinct-row ks reads are <=2-way
//    per bank quad (free), no padding needed.
// Whole K (64 words) fits in one 64KB LDS tile: single load, single barrier.
__launch_bounds__(256, 2)
__global__ void bgemm_kernel(const unsigned int* __restrict__ xb,   // [B][64]
                             const unsigned int* __restrict__ kb,   // [U][64]
                             const float* __restrict__ bias,
                             float* __restrict__ out) {
    __shared__ unsigned int xs[128 * KWORDS];   // 32KB
    __shared__ unsigned int ks[128 * KWORDS];   // 32KB

    const int bx  = blockIdx.x;   // col tile (16)
    const int by  = blockIdx.y;   // row tile (64)
    const int tid = threadIdx.x;

    // Contiguous 32KB chunks -> fully coalesced uint4 loads, swizzled store.
    const uint4* xsrc = (const uint4*)(xb + (size_t)(by * 128) * KWORDS);
    const uint4* ksrc = (const uint4*)(kb + (size_t)(bx * 128) * KWORDS);
#pragma unroll
    for (int i = 0; i < 8; i++) {
        int flat = tid + i * 256;          // uint4 index 0..2047
        int r    = flat >> 4;              // 16 uint4 per 64-word row
        int w4   = flat & 15;
        int sw4  = w4 ^ ((r >> 3) & 7);
        uint4 xv = xsrc[flat];
        uint4 kv = ksrc[flat];
        *((uint4*)&xs[r * KWORDS + sw4 * 4]) = xv;
        *((uint4*)&ks[r * KWORDS + sw4 * 4]) = kv;
    }
    __syncthreads();

    const int tr  = (tid >> 4) * 8;        // thread's 8 rows
    const int tc  = (tid & 15) * 8;        // thread's 8 cols
    const int xsw = (tid >> 4) & 7;        // swizzle for rows tr..tr+7 (row>>3 == tid>>4)
    const int ksw = (tid & 15) & 7;        // swizzle for rows tc..tc+7
    int acc[8][8] = {};

    for (int w4 = 0; w4 < 16; w4++) {
        uint4 xv[8], kv[8];
        const int xcol = (w4 ^ xsw) * 4;
        const int kcol = (w4 ^ ksw) * 4;
#pragma unroll
        for (int r = 0; r < 8; r++) xv[r] = *((const uint4*)&xs[(tr + r) * KWORDS + xcol]);
#pragma unroll
        for (int c = 0; c < 8; c++) kv[c] = *((const uint4*)&ks[(tc + c) * KWORDS + kcol]);
#pragma unroll
        for (int r = 0; r < 8; r++)
#pragma unroll
            for (int c = 0; c < 8; c++) {
                acc[r][c] += __popc(xv[r].x ^ kv[c].x);
                acc[r][c] += __popc(xv[r].y ^ kv[c].y);
                acc[r][c] += __popc(xv[r].z ^ kv[c].z);
                acc[r][c] += __popc(xv[r].w ^ kv[c].w);
            }
    }

    const int row0 = by * 128 + tr;
    const int col0 = bx * 128 + tc;
    const float4 b0 = *((const float4*)&bias[col0]);
    const float4 b1 = *((const float4*)&bias[col0 + 4]);
#pragma unroll
    for (int r = 0; r < 8; r++) {
        float4 o0, o1;
        o0.x = (float)(D_DIM - 2 * acc[r][0]) + b0.x;
        o0.y = (float)(D_DIM - 2 * acc[r][1]) + b0.y;
        o0.z = (float)(D_DIM - 2 * acc[r][2]) + b0.z;
        o0.w = (float)(D_DIM - 2 * acc[r][3]) + b0.w;
        o1.x = (float)(D_DIM - 2 * acc[r][4]) + b1.x;
        o1.y = (float)(D_DIM - 2 * acc[r][5]) + b1.y;
        o1.z = (float)(D_DIM - 2 * acc[r][6]) + b1.z;
        o1.w = (float)(D_DIM - 2 * acc[r][7]) + b1.w;
        float* orow = &out[(size_t)(row0 + r) * U_DIM + col0];
        *((float4*)orow)       = o0;
        *((float4*)(orow + 4)) = o1;
    }
}

extern "C" void kernel_launch(void* const* d_in, const int* in_sizes, int n_in,
                              void* d_out, int out_size, void* d_ws, size_t ws_size,
                              hipStream_t stream) {
    const float* x    = (const float*)d_in[0];   // [8192][2048]
    const float* k    = (const float*)d_in[1];   // [2048][2048]
    const float* bias = (const float*)d_in[2];   // [2048]
    float* out = (float*)d_out;

    unsigned long long* xbits = (unsigned long long*)d_ws;                       // 2 MB
    unsigned long long* kbits = (unsigned long long*)((char*)d_ws + (size_t)B_DIM * (D_DIM / 8)); // 0.5 MB

    // pack x: 1024 elements per 256-thread block
    pack_x_kernel<<<(B_DIM * D_DIM) / 1024, 256, 0, stream>>>(x, xbits);
    // pack k: 32x32 tiles of 64x64
    pack_k_kernel<<<32 * 32, 256, 0, stream>>>(k, kbits);
    // bit-GEMM: 16 col tiles x 64 row tiles
    dim3 grid(U_DIM / 128, B_DIM / 128);
    bgemm_kernel<<<grid, 256, 0, stream>>>((const unsigned int*)xbits,
                                           (const unsigned int*)kbits, bias, out);
}